// Round 1
// baseline (69.812 us; speedup 1.0000x reference)
//
#include <hip/hip_runtime.h>

#define BATCH 32
#define LSEQ 4096
#define HDIM 512

// -----------------------------------------------------------------------------
// Kernel 1: v[b,h] = sum_o h_last[b,o] * W[o,h];  c[b] = h_last[b,:] . bias
// h_last[b,:] = hidden[0, 1, b, :]  (flat offset (BATCH + b)*HDIM)
// grid = BATCH blocks, block = HDIM threads
// -----------------------------------------------------------------------------
__global__ __launch_bounds__(HDIM) void proj_kernel(
    const float* __restrict__ hidden, const float* __restrict__ W,
    const float* __restrict__ bias, float* __restrict__ v, float* __restrict__ c)
{
    const int b = blockIdx.x;
    const int h = threadIdx.x;

    __shared__ float s_hl[HDIM];
    s_hl[h] = hidden[(BATCH + b) * HDIM + h];
    __syncthreads();

    float acc = 0.f;
#pragma unroll 8
    for (int o = 0; o < HDIM; ++o) {
        acc += s_hl[o] * W[o * HDIM + h];   // coalesced across threads
    }
    v[b * HDIM + h] = acc;

    // c[b] = sum_o s_hl[o]*bias[o]  (block reduce)
    float p = s_hl[h] * bias[h];
#pragma unroll
    for (int off = 1; off < 64; off <<= 1) p += __shfl_xor(p, off, 64);

    __shared__ float red[HDIM / 64];
    const int wid  = h >> 6;
    const int lane = h & 63;
    if (lane == 0) red[wid] = p;
    __syncthreads();
    if (h == 0) {
        float s = 0.f;
#pragma unroll
        for (int w = 0; w < HDIM / 64; ++w) s += red[w];
        c[b] = s;
    }
}

// -----------------------------------------------------------------------------
// Kernel 2: energies[b,l] = enc[b,l,:] . v[b,:] + c[b]
// One wave (64 lanes) per row; lane loads 8 floats (2x float4), butterfly reduce.
// 4 waves (256 threads) per block -> 4 rows/block. Writes into d_out (as f32).
// -----------------------------------------------------------------------------
__global__ __launch_bounds__(256) void energy_kernel(
    const float* __restrict__ enc, const float* __restrict__ v,
    const float* __restrict__ c, float* __restrict__ energies)
{
    const int wave = threadIdx.x >> 6;
    const int lane = threadIdx.x & 63;
    const long r = (long)blockIdx.x * 4 + wave;       // row in [0, BATCH*LSEQ)
    const int b = (int)(r >> 12);                     // r / LSEQ

    const float4* ep = (const float4*)(enc + r * HDIM) + lane * 2;
    const float4* vp = (const float4*)(v + (long)b * HDIM) + lane * 2;

    const float4 e0 = ep[0], e1 = ep[1];
    const float4 v0 = vp[0], v1 = vp[1];

    float d = e0.x * v0.x + e0.y * v0.y + e0.z * v0.z + e0.w * v0.w
            + e1.x * v1.x + e1.y * v1.y + e1.z * v1.z + e1.w * v1.w;

#pragma unroll
    for (int off = 1; off < 64; off <<= 1) d += __shfl_xor(d, off, 64);

    if (lane == 0) energies[r] = d + c[b];
}

// -----------------------------------------------------------------------------
// Kernel 3: softmax over L per batch row, in place on d_out.
// 32 blocks x 256 threads, 16 elems (4x float4) per thread, all in registers.
// -----------------------------------------------------------------------------
__global__ __launch_bounds__(256) void softmax_kernel(float* __restrict__ out)
{
    const int b = blockIdx.x;
    const int t = threadIdx.x;
    const int wid  = t >> 6;
    const int lane = t & 63;

    float4* o4 = (float4*)(out + (long)b * LSEQ);

    float4 vals[4];
    float m = -3.402823466e+38f;
#pragma unroll
    for (int i = 0; i < 4; ++i) {
        vals[i] = o4[i * 256 + t];                    // coalesced
        m = fmaxf(m, fmaxf(fmaxf(vals[i].x, vals[i].y),
                           fmaxf(vals[i].z, vals[i].w)));
    }

    // block max
    __shared__ float smax[4];
#pragma unroll
    for (int off = 1; off < 64; off <<= 1) m = fmaxf(m, __shfl_xor(m, off, 64));
    if (lane == 0) smax[wid] = m;
    __syncthreads();
    m = fmaxf(fmaxf(smax[0], smax[1]), fmaxf(smax[2], smax[3]));

    // exp + block sum
    float s = 0.f;
#pragma unroll
    for (int i = 0; i < 4; ++i) {
        vals[i].x = __expf(vals[i].x - m);
        vals[i].y = __expf(vals[i].y - m);
        vals[i].z = __expf(vals[i].z - m);
        vals[i].w = __expf(vals[i].w - m);
        s += vals[i].x + vals[i].y + vals[i].z + vals[i].w;
    }
    __shared__ float ssum[4];
#pragma unroll
    for (int off = 1; off < 64; off <<= 1) s += __shfl_xor(s, off, 64);
    if (lane == 0) ssum[wid] = s;
    __syncthreads();
    s = ssum[0] + ssum[1] + ssum[2] + ssum[3];

    const float inv = 1.0f / s;
#pragma unroll
    for (int i = 0; i < 4; ++i) {
        float4 w = vals[i];
        w.x *= inv; w.y *= inv; w.z *= inv; w.w *= inv;
        o4[i * 256 + t] = w;
    }
}

// -----------------------------------------------------------------------------
extern "C" void kernel_launch(void* const* d_in, const int* in_sizes, int n_in,
                              void* d_out, int out_size, void* d_ws, size_t ws_size,
                              hipStream_t stream)
{
    const float* hidden = (const float*)d_in[0];   // (2,2,B,H)
    const float* enc    = (const float*)d_in[1];   // (B,L,H)
    const float* W      = (const float*)d_in[2];   // (H,H)
    const float* bias   = (const float*)d_in[3];   // (H,)

    float* ws = (float*)d_ws;
    float* v  = ws;                    // B*H floats
    float* c  = ws + BATCH * HDIM;     // B floats

    float* out = (float*)d_out;        // B*L floats; used as energies scratch too

    proj_kernel<<<BATCH, HDIM, 0, stream>>>(hidden, W, bias, v, c);
    energy_kernel<<<(BATCH * LSEQ) / 4, 256, 0, stream>>>(enc, v, c, out);
    softmax_kernel<<<BATCH, 256, 0, stream>>>(out);
}

// Round 3
// 61.293 us; speedup vs baseline: 1.1390x; 1.1390x over previous
//
#include <hip/hip_runtime.h>

#define BATCH 32
#define LSEQ 4096
#define HDIM 512

typedef float f32x4 __attribute__((ext_vector_type(4)));

// -----------------------------------------------------------------------------
// Kernel 1: partial projection. grid (BATCH, 2), block 512.
// vpart[part][b][h] = sum_{o in half} h_last[b][o] * W[o][h]
// cpart[part][b]    = sum_{o in half} h_last[b][o] * bias[o]
// h_last[b,:] = hidden[0, 1, b, :] (flat offset (BATCH + b)*HDIM)
// -----------------------------------------------------------------------------
__global__ __launch_bounds__(512) void proj_kernel(
    const float* __restrict__ hidden, const float* __restrict__ W,
    const float* __restrict__ bias, float* __restrict__ vpart,
    float* __restrict__ cpart)
{
    const int b    = blockIdx.x;
    const int part = blockIdx.y;
    const int h    = threadIdx.x;
    const int obase = part * (HDIM / 2);

    __shared__ float s_hl[HDIM / 2];
    if (h < HDIM / 2) s_hl[h] = hidden[(BATCH + b) * HDIM + obase + h];
    __syncthreads();

    float acc = 0.f;
#pragma unroll 16
    for (int o = 0; o < HDIM / 2; ++o) {
        acc += s_hl[o] * W[(obase + o) * HDIM + h];   // coalesced across threads
    }
    vpart[(part * BATCH + b) * HDIM + h] = acc;

    // partial c
    float p = (h < HDIM / 2) ? s_hl[h] * bias[obase + h] : 0.f;
#pragma unroll
    for (int off = 1; off < 64; off <<= 1) p += __shfl_xor(p, off, 64);

    __shared__ float red[8];
    const int wid  = h >> 6;
    const int lane = h & 63;
    if (lane == 0) red[wid] = p;
    __syncthreads();
    if (h == 0) {
        float s = 0.f;
#pragma unroll
        for (int w = 0; w < 8; ++w) s += red[w];
        cpart[part * BATCH + b] = s;
    }
}

// -----------------------------------------------------------------------------
// Kernel 2: energies[b,l] = enc[b,l,:] . (vA[b,:]+vB[b,:]) + cA[b]+cB[b]
// 4 rows per wave: 8 nontemporal float4 enc loads in flight, one v read and
// one 6-level butterfly (4 interleaved chains) per 4 rows. Lane 0 stores a
// float4 of energies. Block 256 = 4 waves = 16 rows; grid 8192.
// -----------------------------------------------------------------------------
__global__ __launch_bounds__(256) void energy_kernel(
    const float* __restrict__ enc, const float* __restrict__ vA,
    const float* __restrict__ vB, const float* __restrict__ cA,
    const float* __restrict__ cB, float* __restrict__ energies)
{
    const int wave = threadIdx.x >> 6;
    const int lane = threadIdx.x & 63;
    const long r0 = (long)blockIdx.x * 16 + wave * 4;   // first of 4 rows
    const int b = (int)(r0 >> 12);                      // r0 / LSEQ (rows share b)

    const f32x4* e4 = (const f32x4*)(enc + r0 * HDIM) + lane * 2;
    const float4* va = (const float4*)(vA + (long)b * HDIM) + lane * 2;
    const float4* vb = (const float4*)(vB + (long)b * HDIM) + lane * 2;

    // issue all enc loads (nontemporal: streaming, don't pollute cache)
    f32x4 e[8];
#pragma unroll
    for (int j = 0; j < 4; ++j) {
        e[2 * j]     = __builtin_nontemporal_load(e4 + j * 128);
        e[2 * j + 1] = __builtin_nontemporal_load(e4 + j * 128 + 1);
    }
    float4 v0 = va[0], v1 = va[1];
    const float4 w0 = vb[0], w1 = vb[1];
    v0.x += w0.x; v0.y += w0.y; v0.z += w0.z; v0.w += w0.w;
    v1.x += w1.x; v1.y += w1.y; v1.z += w1.z; v1.w += w1.w;

    float d[4];
#pragma unroll
    for (int j = 0; j < 4; ++j) {
        const f32x4 a = e[2 * j], c = e[2 * j + 1];
        d[j] = a.x * v0.x + a.y * v0.y + a.z * v0.z + a.w * v0.w
             + c.x * v1.x + c.y * v1.y + c.z * v1.z + c.w * v1.w;
    }

#pragma unroll
    for (int off = 1; off < 64; off <<= 1) {
#pragma unroll
        for (int j = 0; j < 4; ++j) d[j] += __shfl_xor(d[j], off, 64);
    }

    if (lane == 0) {
        const float cb = cA[b] + cB[b];
        float4 out = { d[0] + cb, d[1] + cb, d[2] + cb, d[3] + cb };
        *(float4*)(energies + r0) = out;
    }
}

// -----------------------------------------------------------------------------
// Kernel 3: softmax over L per batch row, in place on d_out.
// 32 blocks x 512 threads, 8 elems (2x float4) per thread.
// -----------------------------------------------------------------------------
__global__ __launch_bounds__(512) void softmax_kernel(float* __restrict__ out)
{
    const int b = blockIdx.x;
    const int t = threadIdx.x;
    const int wid  = t >> 6;
    const int lane = t & 63;

    float4* o4 = (float4*)(out + (long)b * LSEQ);

    float4 v0 = o4[t], v1 = o4[512 + t];
    float m = fmaxf(fmaxf(fmaxf(v0.x, v0.y), fmaxf(v0.z, v0.w)),
                    fmaxf(fmaxf(v1.x, v1.y), fmaxf(v1.z, v1.w)));

    __shared__ float smax[8];
#pragma unroll
    for (int off = 1; off < 64; off <<= 1) m = fmaxf(m, __shfl_xor(m, off, 64));
    if (lane == 0) smax[wid] = m;
    __syncthreads();
#pragma unroll
    for (int w = 0; w < 8; ++w) m = fmaxf(m, smax[w]);

    v0.x = __expf(v0.x - m); v0.y = __expf(v0.y - m);
    v0.z = __expf(v0.z - m); v0.w = __expf(v0.w - m);
    v1.x = __expf(v1.x - m); v1.y = __expf(v1.y - m);
    v1.z = __expf(v1.z - m); v1.w = __expf(v1.w - m);

    float s = v0.x + v0.y + v0.z + v0.w + v1.x + v1.y + v1.z + v1.w;
    __shared__ float ssum[8];
#pragma unroll
    for (int off = 1; off < 64; off <<= 1) s += __shfl_xor(s, off, 64);
    if (lane == 0) ssum[wid] = s;
    __syncthreads();
    s = 0.f;
#pragma unroll
    for (int w = 0; w < 8; ++w) s += ssum[w];

    const float inv = 1.0f / s;
    v0.x *= inv; v0.y *= inv; v0.z *= inv; v0.w *= inv;
    v1.x *= inv; v1.y *= inv; v1.z *= inv; v1.w *= inv;
    o4[t] = v0;
    o4[512 + t] = v1;
}

// -----------------------------------------------------------------------------
extern "C" void kernel_launch(void* const* d_in, const int* in_sizes, int n_in,
                              void* d_out, int out_size, void* d_ws, size_t ws_size,
                              hipStream_t stream)
{
    const float* hidden = (const float*)d_in[0];   // (2,2,B,H)
    const float* enc    = (const float*)d_in[1];   // (B,L,H)
    const float* W      = (const float*)d_in[2];   // (H,H)
    const float* bias   = (const float*)d_in[3];   // (H,)

    float* ws    = (float*)d_ws;
    float* vpart = ws;                               // 2*B*H floats
    float* cpart = ws + 2 * BATCH * HDIM;            // 2*B floats

    float* out = (float*)d_out;                      // B*L floats (energies scratch)

    proj_kernel<<<dim3(BATCH, 2), 512, 0, stream>>>(hidden, W, bias, vpart, cpart);
    energy_kernel<<<(BATCH * LSEQ) / 16, 256, 0, stream>>>(
        enc, vpart, vpart + BATCH * HDIM, cpart, cpart + BATCH, out);
    softmax_kernel<<<BATCH, 512, 0, stream>>>(out);
}

// Round 4
// 57.916 us; speedup vs baseline: 1.2054x; 1.0583x over previous
//
#include <hip/hip_runtime.h>

#define BATCH 32
#define LSEQ 4096
#define HDIM 512
#define PARTS 4

typedef float f32x4 __attribute__((ext_vector_type(4)));

// -----------------------------------------------------------------------------
// Kernel 1: partial projection. grid (BATCH, PARTS), block 512.
// vpart[p][b][h] = sum_{o in slice p} h_last[b][o] * W[o][h]
// cpart[p][b]    = sum_{o in slice p} h_last[b][o] * bias[o]
// h_last[b,:] = hidden[0, 1, b, :] (flat offset (BATCH + b)*HDIM)
// -----------------------------------------------------------------------------
__global__ __launch_bounds__(512) void proj_kernel(
    const float* __restrict__ hidden, const float* __restrict__ W,
    const float* __restrict__ bias, float* __restrict__ vpart,
    float* __restrict__ cpart)
{
    const int b    = blockIdx.x;
    const int part = blockIdx.y;
    const int h    = threadIdx.x;
    const int OS   = HDIM / PARTS;          // 128
    const int obase = part * OS;

    __shared__ float s_hl[HDIM / PARTS];
    if (h < OS) s_hl[h] = hidden[(BATCH + b) * HDIM + obase + h];
    __syncthreads();

    float acc = 0.f;
#pragma unroll 16
    for (int o = 0; o < OS; ++o) {
        acc += s_hl[o] * W[(obase + o) * HDIM + h];   // coalesced across threads
    }
    vpart[(part * BATCH + b) * HDIM + h] = acc;

    // partial c
    float p = (h < OS) ? s_hl[h] * bias[obase + h] : 0.f;
#pragma unroll
    for (int off = 1; off < 64; off <<= 1) p += __shfl_xor(p, off, 64);

    __shared__ float red[8];
    const int wid  = h >> 6;
    const int lane = h & 63;
    if (lane == 0) red[wid] = p;
    __syncthreads();
    if (h == 0) {
        float s = 0.f;
#pragma unroll
        for (int w = 0; w < 8; ++w) s += red[w];
        cpart[part * BATCH + b] = s;
    }
}

// -----------------------------------------------------------------------------
// Kernel 2: energies[b,l] = enc[b,l,:] . v[b,:] + c[b]
// 16 lanes per row: sub = lane>>4 picks one of 4 rows, sl = lane&15 picks
// float4 chunks sl, sl+16, ..., sl+112 (stride 256B; each 16-lane quarter
// reads a contiguous 256B segment -> coalesced). Row reduce = 4 shuffle
// levels within the 16-lane group. v (sum of 4 partials) + c hoisted per
// wave; 8 batches of 4 rows = 32 rows per wave. Block 256 = 4 waves = 128
// rows, all of one b. grid = 32*4096/128 = 1024.
// -----------------------------------------------------------------------------
__global__ __launch_bounds__(256) void energy_kernel(
    const float* __restrict__ enc, const float* __restrict__ vpart,
    const float* __restrict__ cpart, float* __restrict__ energies)
{
    const int wave = threadIdx.x >> 6;
    const int lane = threadIdx.x & 63;
    const int sub  = lane >> 4;
    const int sl   = lane & 15;

    const int b      = blockIdx.x >> 5;            // 32 blocks per batch row
    const int l_base = (blockIdx.x & 31) * 128 + wave * 32;

    // hoist v = sum of 4 partials (L1/L2-resident, 2KB per b per part)
    const f32x4* vp0 = (const f32x4*)(vpart + (0 * BATCH + b) * HDIM);
    const f32x4* vp1 = (const f32x4*)(vpart + (1 * BATCH + b) * HDIM);
    const f32x4* vp2 = (const f32x4*)(vpart + (2 * BATCH + b) * HDIM);
    const f32x4* vp3 = (const f32x4*)(vpart + (3 * BATCH + b) * HDIM);
    f32x4 vv[8];
#pragma unroll
    for (int k = 0; k < 8; ++k) {
        const int ch = sl + 16 * k;
        vv[k] = vp0[ch] + vp1[ch] + vp2[ch] + vp3[ch];
    }
    const float cb = cpart[b] + cpart[BATCH + b] + cpart[2 * BATCH + b]
                   + cpart[3 * BATCH + b];

    const long rbase = (long)b * LSEQ + l_base;

#pragma unroll 2
    for (int batch = 0; batch < 8; ++batch) {
        const long r = rbase + batch * 4 + sub;
        const f32x4* ep = (const f32x4*)(enc + r * HDIM) + sl;

        f32x4 e[8];
#pragma unroll
        for (int k = 0; k < 8; ++k)
            e[k] = __builtin_nontemporal_load(ep + 16 * k);

        float d = 0.f;
#pragma unroll
        for (int k = 0; k < 8; ++k) {
            d += e[k].x * vv[k].x + e[k].y * vv[k].y
               + e[k].z * vv[k].z + e[k].w * vv[k].w;
        }

        // reduce across the 16-lane group (bits 0..3 of lane)
        d += __shfl_xor(d, 1, 64);
        d += __shfl_xor(d, 2, 64);
        d += __shfl_xor(d, 4, 64);
        d += __shfl_xor(d, 8, 64);

        if (sl == 0) energies[r] = d + cb;   // lanes 0,16,32,48 -> 16B segment
    }
}

// -----------------------------------------------------------------------------
// Kernel 3: softmax over L per batch row, in place on d_out.
// 32 blocks x 1024 threads, 1 float4 per thread.
// -----------------------------------------------------------------------------
__global__ __launch_bounds__(1024) void softmax_kernel(float* __restrict__ out)
{
    const int b = blockIdx.x;
    const int t = threadIdx.x;
    const int wid  = t >> 6;
    const int lane = t & 63;

    float4* o4 = (float4*)(out + (long)b * LSEQ);

    float4 v0 = o4[t];
    float m = fmaxf(fmaxf(v0.x, v0.y), fmaxf(v0.z, v0.w));

    __shared__ float smax[16];
#pragma unroll
    for (int off = 1; off < 64; off <<= 1) m = fmaxf(m, __shfl_xor(m, off, 64));
    if (lane == 0) smax[wid] = m;
    __syncthreads();
#pragma unroll
    for (int w = 0; w < 16; ++w) m = fmaxf(m, smax[w]);

    v0.x = __expf(v0.x - m); v0.y = __expf(v0.y - m);
    v0.z = __expf(v0.z - m); v0.w = __expf(v0.w - m);

    float s = v0.x + v0.y + v0.z + v0.w;
    __shared__ float ssum[16];
#pragma unroll
    for (int off = 1; off < 64; off <<= 1) s += __shfl_xor(s, off, 64);
    if (lane == 0) ssum[wid] = s;
    __syncthreads();
    s = 0.f;
#pragma unroll
    for (int w = 0; w < 16; ++w) s += ssum[w];

    const float inv = 1.0f / s;
    v0.x *= inv; v0.y *= inv; v0.z *= inv; v0.w *= inv;
    o4[t] = v0;
}

// -----------------------------------------------------------------------------
extern "C" void kernel_launch(void* const* d_in, const int* in_sizes, int n_in,
                              void* d_out, int out_size, void* d_ws, size_t ws_size,
                              hipStream_t stream)
{
    const float* hidden = (const float*)d_in[0];   // (2,2,B,H)
    const float* enc    = (const float*)d_in[1];   // (B,L,H)
    const float* W      = (const float*)d_in[2];   // (H,H)
    const float* bias   = (const float*)d_in[3];   // (H,)

    float* ws    = (float*)d_ws;
    float* vpart = ws;                               // PARTS*B*H floats
    float* cpart = ws + PARTS * BATCH * HDIM;        // PARTS*B floats

    float* out = (float*)d_out;                      // B*L floats (energies scratch)

    proj_kernel<<<dim3(BATCH, PARTS), 512, 0, stream>>>(hidden, W, bias, vpart, cpart);
    energy_kernel<<<(BATCH * LSEQ) / 128, 256, 0, stream>>>(enc, vpart, cpart, out);
    softmax_kernel<<<BATCH, 1024, 0, stream>>>(out);
}